// Round 7
// baseline (300.633 us; speedup 1.0000x reference)
//
#include <hip/hip_runtime.h>
#include <hip/hip_bf16.h>

#define N_NODES 50000
#define N_EDGES 800000
#define IN_F 256
#define OUT_F 64

#define NCH 4  // dst chains per wave in gather

// ---------------- GEMM: h(bf16) = x @ W ----------------
// Wave = 8 nodes, lane = feature. Node base forced wave-uniform via
// readfirstlane -> x loads take the SCALAR path (s_load, lgkmcnt), W loads
// per-lane coalesced VMEM (L1-resident, vmcnt). No LDS, no barriers:
// removes the 12cyc/16B ds_read broadcast bound of the R3 kernel.
__global__ __launch_bounds__(256) void gc_gemm(const float* __restrict__ x,
                                               const float* __restrict__ W,
                                               ushort* __restrict__ h) {
    const int f = threadIdx.x & 63;
    const int gw = __builtin_amdgcn_readfirstlane(blockIdx.x * 4 + (threadIdx.x >> 6));
    const int n0 = gw * 8;
    if (n0 >= N_NODES) return;  // 50000 % 8 == 0

    const float* __restrict__ xr = x + (size_t)n0 * IN_F;  // uniform pointer
    const float* __restrict__ Wf = W + f;

    float acc[8];
#pragma unroll
    for (int j = 0; j < 8; ++j) acc[j] = 0.f;

#pragma unroll 1
    for (int k = 0; k < IN_F; k += 4) {
        const float w0 = Wf[(k + 0) * OUT_F];
        const float w1 = Wf[(k + 1) * OUT_F];
        const float w2 = Wf[(k + 2) * OUT_F];
        const float w3 = Wf[(k + 3) * OUT_F];
#pragma unroll
        for (int j = 0; j < 8; ++j) {
            // uniform addresses -> s_load_dwordx4
            const float x0 = xr[j * IN_F + k + 0];
            const float x1 = xr[j * IN_F + k + 1];
            const float x2 = xr[j * IN_F + k + 2];
            const float x3 = xr[j * IN_F + k + 3];
            acc[j] += x0 * w0 + x1 * w1 + x2 * w2 + x3 * w3;
        }
    }

#pragma unroll
    for (int j = 0; j < 8; ++j) {
        __hip_bfloat16 b = __float2bfloat16(acc[j]);
        h[(size_t)(n0 + j) * OUT_F + f] = *(ushort*)&b;
    }
}

// ---------------- linked-list adjacency build (packed) ----------------
// packed[i] = {src, bits(ew), next, pad} written coalesced 16B; only the 4B
// head exchange scatters.
__global__ __launch_bounds__(256) void gc_link(const int* __restrict__ src,
                                               const int* __restrict__ dst,
                                               const float* __restrict__ ew,
                                               int* __restrict__ head,
                                               int4* __restrict__ packed) {
    const int i = blockIdx.x * blockDim.x + threadIdx.x;
    if (i < N_EDGES) {
        const int old = atomicExch(&head[dst[i]], i);
        packed[i] = make_int4(src[i], __float_as_int(ew[i]), old, 0);
    }
}

// ---------------- gather: out[d] = bias + sum w*h[src] via chain walk -------
// One wave = NCH chains, lane = feature. Per edge step: ONE 16B broadcast
// packed load + ONE 128B coalesced bf16 h-row load. 4 independent chains
// hide the pointer-chase latency.
__global__ __launch_bounds__(256) void gc_gather(const ushort* __restrict__ h,
                                                 const int4* __restrict__ packed,
                                                 const int* __restrict__ head,
                                                 const float* __restrict__ bias,
                                                 float* __restrict__ out) {
    const int gw = (blockIdx.x * blockDim.x + threadIdx.x) >> 6;
    const int f = threadIdx.x & 63;
    const int d0 = gw * NCH;
    if (d0 >= N_NODES) return;

    const float b = bias[f];
    float acc[NCH];
    int e[NCH];
#pragma unroll
    for (int j = 0; j < NCH; ++j) {
        acc[j] = b;
        e[j] = (d0 + j < N_NODES) ? head[d0 + j] : -1;
    }

    for (;;) {
        bool any = false;
        int4 p[NCH];
#pragma unroll
        for (int j = 0; j < NCH; ++j) {
            if (e[j] >= 0) {
                p[j] = packed[e[j]];
                any = true;
            }
        }
        if (!any) break;
#pragma unroll
        for (int j = 0; j < NCH; ++j) {
            if (e[j] >= 0) {
                const ushort hv = h[(size_t)p[j].x * OUT_F + f];
                __hip_bfloat16 hb = *(const __hip_bfloat16*)&hv;
                acc[j] += __int_as_float(p[j].y) * __bfloat162float(hb);
                e[j] = p[j].z;
            }
        }
    }

#pragma unroll
    for (int j = 0; j < NCH; ++j) {
        const int d = d0 + j;
        if (d < N_NODES) out[(size_t)d * OUT_F + f] = acc[j];
    }
}

extern "C" void kernel_launch(void* const* d_in, const int* in_sizes, int n_in,
                              void* d_out, int out_size, void* d_ws, size_t ws_size,
                              hipStream_t stream) {
    const float* x    = (const float*)d_in[0];
    const float* W    = (const float*)d_in[1];
    const float* bias = (const float*)d_in[2];
    const float* ew   = (const float*)d_in[3];
    const int* src    = (const int*)d_in[4];
    const int* dst    = (const int*)d_in[5];
    float* out = (float*)d_out;

    // workspace layout (16B-aligned)
    char* ws = (char*)d_ws;
    ushort* h     = (ushort*)ws;              // 6,400,000 B (bf16 h)
    int*   head   = (int*)(ws + 6400000);     // 200,000 B
    int4*  packed = (int4*)(ws + 6600000);    // 12,800,000 B (end 19.4 MB)

    // head = -1
    hipMemsetAsync(head, 0xFF, (size_t)N_NODES * sizeof(int), stream);

    gc_link<<<(N_EDGES + 255) / 256, 256, 0, stream>>>(src, dst, ew, head, packed);

    gc_gemm<<<(N_NODES / 8 + 3) / 4, 256, 0, stream>>>(x, W, h);

    // 4 waves/block x NCH chains = 16 dsts per block
    gc_gather<<<(N_NODES + 4 * NCH - 1) / (4 * NCH), 256, 0, stream>>>(
        h, packed, head, bias, out);
}

// Round 8
// 213.805 us; speedup vs baseline: 1.4061x; 1.4061x over previous
//
#include <hip/hip_runtime.h>
#include <hip/hip_bf16.h>

#define N_NODES 50000
#define N_EDGES 800000
#define IN_F 256
#define OUT_F 64

#define NCH 4  // dst chains per wave in gather

typedef __attribute__((ext_vector_type(8))) short short8;   // 8 bf16 (4 VGPRs)
typedef __attribute__((ext_vector_type(4))) float f32x4;    // MFMA acc

static __device__ __forceinline__ ushort f2bf(float v) {
    __hip_bfloat16 b = __float2bfloat16(v);
    return *(ushort*)&b;
}

// ---------------- W prep: fp32 W[256][64] -> bf16 B-fragment order ---------
// Wb[((s*8+kk)*64 + lane)*8 + j] = bf16(W[kk*32 + (lane>>4)*8 + j][s*16 + (lane&15)])
// so gemm wave s, k-step kk loads its B-frag as ONE coalesced 16B load.
__global__ __launch_bounds__(256) void gc_wprep(const float* __restrict__ W,
                                                ushort* __restrict__ Wb) {
    const int g = blockIdx.x * 256 + threadIdx.x;  // 2048 groups
    if (g >= 2048) return;
    const int s = g >> 9;
    const int kk = (g >> 6) & 7;
    const int lane = g & 63;
    const int n = s * 16 + (lane & 15);
    const int kb = kk * 32 + (lane >> 4) * 8;
#pragma unroll
    for (int j = 0; j < 8; ++j)
        Wb[(size_t)g * 8 + j] = f2bf(W[(kb + j) * OUT_F + n]);
}

// ---------------- GEMM: h(bf16) = x @ W via MFMA ----------------
// Block = 256 thr = 4 waves, tile = 16 nodes x 64 features (wave = 16-f slice).
// x tile cvt->bf16 staged in LDS (row pad 264 ushorts -> balanced banks);
// B-frags (all K) held in 32 VGPRs; 8 x mfma_f32_16x16x32_bf16 per wave.
__global__ __launch_bounds__(256) void gc_gemm(const float* __restrict__ x,
                                               const ushort* __restrict__ Wb,
                                               ushort* __restrict__ h) {
    __shared__ ushort xs[16 * 264];  // 8448 B
    const int t = threadIdx.x;
    const int nbase = blockIdx.x * 16;  // 50000/16 = 3125 exact

    // stage: 16 rows x 64 float4 = 1024 float4; cvt to bf16
    {
        const float4* __restrict__ xg = (const float4*)(x + (size_t)nbase * IN_F);
#pragma unroll
        for (int i = 0; i < 4; ++i) {
            const int idx = t + i * 256;
            const int node = idx >> 6;
            const int c4 = idx & 63;
            const float4 v = xg[node * 64 + c4];
            ushort4 b;
            b.x = f2bf(v.x); b.y = f2bf(v.y); b.z = f2bf(v.z); b.w = f2bf(v.w);
            *(ushort4*)&xs[node * 264 + c4 * 4] = b;
        }
    }

    const int s = t >> 6;        // wave = feature slice
    const int lane = t & 63;
    const int m = lane & 15;
    const int quad = lane >> 4;

    // B-frags: 8 coalesced 16B loads, resident in VGPRs
    short8 bfrag[8];
#pragma unroll
    for (int kk = 0; kk < 8; ++kk)
        bfrag[kk] = *(const short8*)(Wb + ((size_t)(s * 8 + kk) * 64 + lane) * 8);

    __syncthreads();

    f32x4 acc = {0.f, 0.f, 0.f, 0.f};
#pragma unroll
    for (int kk = 0; kk < 8; ++kk) {
        const short8 afrag = *(const short8*)&xs[m * 264 + kk * 32 + quad * 8];
        acc = __builtin_amdgcn_mfma_f32_16x16x32_bf16(afrag, bfrag[kk], acc, 0, 0, 0);
    }

    // D[row=quad*4+r][col=m] -> h[node][s*16+m]
#pragma unroll
    for (int r = 0; r < 4; ++r) {
        const int row = quad * 4 + r;
        h[(size_t)(nbase + row) * OUT_F + s * 16 + m] = f2bf(acc[r]);
    }
}

// ---------------- linked-list adjacency build (packed) ----------------
__global__ __launch_bounds__(256) void gc_link(const int* __restrict__ src,
                                               const int* __restrict__ dst,
                                               const float* __restrict__ ew,
                                               int* __restrict__ head,
                                               int4* __restrict__ packed) {
    const int i = blockIdx.x * blockDim.x + threadIdx.x;
    if (i < N_EDGES) {
        const int old = atomicExch(&head[dst[i]], i);
        packed[i] = make_int4(src[i], __float_as_int(ew[i]), old, 0);
    }
}

// ---------------- gather: out[d] = bias + sum w*h[src] via chain walk -------
__global__ __launch_bounds__(256) void gc_gather(const ushort* __restrict__ h,
                                                 const int4* __restrict__ packed,
                                                 const int* __restrict__ head,
                                                 const float* __restrict__ bias,
                                                 float* __restrict__ out) {
    const int gw = (blockIdx.x * blockDim.x + threadIdx.x) >> 6;
    const int f = threadIdx.x & 63;
    const int d0 = gw * NCH;
    if (d0 >= N_NODES) return;

    const float b = bias[f];
    float acc[NCH];
    int e[NCH];
#pragma unroll
    for (int j = 0; j < NCH; ++j) {
        acc[j] = b;
        e[j] = (d0 + j < N_NODES) ? head[d0 + j] : -1;
    }

    for (;;) {
        bool any = false;
        int4 p[NCH];
#pragma unroll
        for (int j = 0; j < NCH; ++j) {
            if (e[j] >= 0) {
                p[j] = packed[e[j]];
                any = true;
            }
        }
        if (!any) break;
#pragma unroll
        for (int j = 0; j < NCH; ++j) {
            if (e[j] >= 0) {
                const ushort hv = h[(size_t)p[j].x * OUT_F + f];
                __hip_bfloat16 hb = *(const __hip_bfloat16*)&hv;
                acc[j] += __int_as_float(p[j].y) * __bfloat162float(hb);
                e[j] = p[j].z;
            }
        }
    }

#pragma unroll
    for (int j = 0; j < NCH; ++j) {
        const int d = d0 + j;
        if (d < N_NODES) out[(size_t)d * OUT_F + f] = acc[j];
    }
}

extern "C" void kernel_launch(void* const* d_in, const int* in_sizes, int n_in,
                              void* d_out, int out_size, void* d_ws, size_t ws_size,
                              hipStream_t stream) {
    const float* x    = (const float*)d_in[0];
    const float* W    = (const float*)d_in[1];
    const float* bias = (const float*)d_in[2];
    const float* ew   = (const float*)d_in[3];
    const int* src    = (const int*)d_in[4];
    const int* dst    = (const int*)d_in[5];
    float* out = (float*)d_out;

    // workspace layout (16B-aligned)
    char* ws = (char*)d_ws;
    ushort* h     = (ushort*)ws;               // 6,400,000 B (bf16 h)
    int*    head  = (int*)(ws + 6400000);      // 200,000 B
    int4*   packed= (int4*)(ws + 6600000);     // 12,800,000 B
    ushort* Wb    = (ushort*)(ws + 19400000);  // 32,768 B (end ~19.43 MB)

    gc_wprep<<<8, 256, 0, stream>>>(W, Wb);

    hipMemsetAsync(head, 0xFF, (size_t)N_NODES * sizeof(int), stream);
    gc_link<<<(N_EDGES + 255) / 256, 256, 0, stream>>>(src, dst, ew, head, packed);

    gc_gemm<<<N_NODES / 16, 256, 0, stream>>>(x, Wb, h);

    gc_gather<<<(N_NODES + 4 * NCH - 1) / (4 * NCH), 256, 0, stream>>>(
        h, packed, head, bias, out);
}